// Round 12
// baseline (398.780 us; speedup 1.0000x reference)
//
#include <hip/hip_runtime.h>
#include <hip/hip_bf16.h>
#include <math.h>

#define DEV_INLINE __device__ __forceinline__

typedef __attribute__((ext_vector_type(8))) short bf16x8;
typedef __attribute__((ext_vector_type(8))) unsigned short u16x8;
typedef __attribute__((ext_vector_type(4))) float f32x4;

// ---------------- helpers ----------------

DEV_INLINE void gload_lds16(const void* g, void* l) {
  __builtin_amdgcn_global_load_lds(
      (__attribute__((address_space(1))) unsigned int*)const_cast<void*>(g),
      (__attribute__((address_space(3))) unsigned int*)l,
      16, 0, 0);
}

DEV_INLINE unsigned lds_a(const void* p) {
  return (unsigned)(unsigned long long)(__attribute__((address_space(3))) const void*)p;
}

DEV_INLINE short f2bs(float x) {
  union { __hip_bfloat16 h; short s; } u;
  u.h = __float2bfloat16(x);
  return u.s;
}

DEV_INLINE float bs2f(unsigned short s) {
  union { float f; unsigned u; } v;
  v.u = ((unsigned)s) << 16;
  return v.f;
}

DEV_INLINE f32x4 mfma16(bf16x8 a, bf16x8 b, f32x4 c) {
  return __builtin_amdgcn_mfma_f32_16x16x32_bf16(a, b, c, 0, 0, 0);
}

#define DSREAD_O(dst, base, imm) \
  asm volatile("ds_read_b128 %0, %1 offset:%2" : "=v"(dst) : "v"(base), "n"(imm))

// ---------------- fused prep kernel (unchanged) ----------------

__global__ __launch_bounds__(256)
void prep_all(const float* __restrict__ X, __hip_bfloat16* __restrict__ Xb,
              const float* __restrict__ Wq, const float* __restrict__ Wk,
              const float* __restrict__ Wv, const float* __restrict__ Wo,
              const float* __restrict__ Wi, const float* __restrict__ Wo2,
              __hip_bfloat16* __restrict__ WqkvT, __hip_bfloat16* __restrict__ WoT,
              __hip_bfloat16* __restrict__ WiT, __hip_bfloat16* __restrict__ Wo2T,
              const float* __restrict__ bq, const float* __restrict__ bk,
              const float* __restrict__ bv, float* __restrict__ bqkv)
{
  int bx = blockIdx.x;
  const int tid = threadIdx.x;

  if (bx < 8192) {  // X f32 -> bf16
    const size_t i = ((size_t)bx * 256 + tid) * 4;
    const float4 x = *(const float4*)(X + i);
    union { __hip_bfloat16 h[4]; ushort4 u; } pk;
    pk.h[0] = __float2bfloat16(x.x);
    pk.h[1] = __float2bfloat16(x.y);
    pk.h[2] = __float2bfloat16(x.z);
    pk.h[3] = __float2bfloat16(x.w);
    *(ushort4*)(Xb + i) = pk.u;
    return;
  }
  bx -= 8192;
  if (bx < 4) {  // bias concat
    const int i = bx * 256 + tid;
    bqkv[i] = bq[i]; bqkv[1024 + i] = bk[i]; bqkv[2048 + i] = bv[i];
    return;
  }
  bx -= 4;

  const float* Wsrc; __hip_bfloat16* Wdst; int K, N, nt, kt;
  if (bx < 1024)      { Wsrc = Wq;  Wdst = WqkvT;               K = 1024; N = 1024; nt = bx & 31;  kt = bx >> 5; }
  else if (bx < 2048) { const int l = bx - 1024; Wsrc = Wk;  Wdst = WqkvT + 1024 * 1024; K = 1024; N = 1024; nt = l & 31;  kt = l >> 5; }
  else if (bx < 3072) { const int l = bx - 2048; Wsrc = Wv;  Wdst = WqkvT + 2048 * 1024; K = 1024; N = 1024; nt = l & 31;  kt = l >> 5; }
  else if (bx < 4096) { const int l = bx - 3072; Wsrc = Wo;  Wdst = WoT;  K = 1024; N = 1024; nt = l & 31;  kt = l >> 5; }
  else if (bx < 8192) { const int l = bx - 4096; Wsrc = Wi;  Wdst = WiT;  K = 1024; N = 4096; nt = l & 127; kt = l >> 7; }
  else                { const int l = bx - 8192; Wsrc = Wo2; Wdst = Wo2T; K = 4096; N = 1024; nt = l & 31;  kt = l >> 5; }

  __shared__ float t[32][33];
  const int n0 = nt * 32, k0 = kt * 32;
  const int tx = tid & 31, ty = tid >> 5;
#pragma unroll
  for (int r = ty; r < 32; r += 8)
    t[r][tx] = Wsrc[(size_t)(k0 + r) * N + n0 + tx];
  __syncthreads();
#pragma unroll
  for (int r = ty; r < 32; r += 8)
    Wdst[(size_t)(n0 + r) * K + k0 + tx] = __float2bfloat16(t[tx][r]);
}

// ====== ring-of-3 pipelined GEMM: C = A[M,K] @ Bt[N,K]^T ======
// 128x128 tile, 4 waves (2x2), BK=32. THREE 16KB LDS buffers (A 8K + B 8K).
// Step t: vmcnt(4) [tile t's 4 per-wave loads landed; t+1's may fly] ->
// s_barrier -> issue stage(t+2) -> 8 asm ds_read of buf[t%3] -> lgkmcnt(0)
// -> 16 MFMA in setprio. Issue-to-use distance = 2 full steps. One barrier
// per K-step; NO vmcnt(0) drain in steady state; no "memory" clobbers
// (ordering via sched_barrier(0) only).
// Rows 64B (BK=32), 4 slots/row; LDS slot s holds global slot s^(row&3)
// via pre-swizzled source; read slot = q4^(c16&3).
// MODE 0: bf16(acc+bias); 2: bf16(gelu(acc+bias));
// MODE 3: bf16(acc+bias+f32 resid); 4: bf16(acc+bias+bf16 resid)

template<int MODE>
DEV_INLINE void gemmr3_body(const short* __restrict__ A, const short* __restrict__ Bt,
                            const float* __restrict__ bias,
                            const float* __restrict__ residf,
                            const unsigned short* __restrict__ residb,
                            __hip_bfloat16* __restrict__ Cb,
                            int M, int N, int K)
{
  __shared__ __align__(128) short lds[24576];   // 48KB = 3 x (A 8KB + B 8KB)

  const int tid = threadIdx.x;
  const int lane = tid & 63, w = tid >> 6;
  const int q4 = lane >> 4, c16 = lane & 15;
  const int wm = (w >> 1) * 64, wn = (w & 1) * 64;

  const int nNT = N >> 7;
  int bid = blockIdx.x;
  { const int cpx = (int)gridDim.x >> 3; bid = (bid & 7) * cpx + (bid >> 3); }
  const int bm = (bid / nNT) * 128;
  const int bn = (bid % nNT) * 128;

  // staging: thread t -> row sr=t>>2 (0..63), slot sl=t&3; global slot
  // pre-swizzled ^(row&3). Two row-groups per operand (rows 0-63, 64-127).
  const int sr = tid >> 2, sl = tid & 3;
  const int sg = (sl ^ (sr & 3)) * 8;
  const short* pA0 = A  + (size_t)(bm + sr) * K + sg;
  const short* pA1 = A  + (size_t)(bm + 64 + sr) * K + ((sl ^ ((sr + 64) & 3)) * 8);
  const short* pB0 = Bt + (size_t)(bn + sr) * K + sg;
  const short* pB1 = Bt + (size_t)(bn + 64 + sr) * K + ((sl ^ ((sr + 64) & 3)) * 8);

  // ds_read bases (slot swizzled); buffer offset added at read time
  const unsigned aRd = lds_a(lds) + (unsigned)((wm + c16) * 64 + (q4 ^ (c16 & 3)) * 16);
  const unsigned bRd = lds_a(lds) + (unsigned)(8192 + (wn + c16) * 64 + (q4 ^ (c16 & 3)) * 16);

  f32x4 acc[4][4];
#pragma unroll
  for (int i = 0; i < 4; ++i)
#pragma unroll
    for (int j = 0; j < 4; ++j) acc[i][j] = (f32x4){0.f, 0.f, 0.f, 0.f};

  auto stage = [&](unsigned off, int kt) {
    char* b = (char*)lds + off;
    gload_lds16(pA0 + kt, b + w * 1024);
    gload_lds16(pA1 + kt, b + 4096 + w * 1024);
    gload_lds16(pB0 + kt, b + 8192 + w * 1024);
    gload_lds16(pB1 + kt, b + 12288 + w * 1024);
  };

  // prologue: stage tiles 0 and 1 into buf0, buf1
  stage(0, 0);
  stage(16384, 32);

  const int NT = K >> 5;
  unsigned off = 0, soff = 32768;
  for (int t = 0; t < NT; ++t) {
    __builtin_amdgcn_sched_barrier(0);
    if (t < NT - 1) { asm volatile("s_waitcnt vmcnt(4)"); }
    else            { asm volatile("s_waitcnt vmcnt(0)"); }
    asm volatile("s_barrier");
    __builtin_amdgcn_sched_barrier(0);
    if (t + 2 < NT) stage(soff, (t + 2) << 5);
    __builtin_amdgcn_sched_barrier(0);

    bf16x8 a0, a1, a2, a3, b0, b1, b2, b3;
    DSREAD_O(a0, aRd + off, 0 * 1024); DSREAD_O(a1, aRd + off, 1 * 1024);
    DSREAD_O(a2, aRd + off, 2 * 1024); DSREAD_O(a3, aRd + off, 3 * 1024);
    DSREAD_O(b0, bRd + off, 0 * 1024); DSREAD_O(b1, bRd + off, 1 * 1024);
    DSREAD_O(b2, bRd + off, 2 * 1024); DSREAD_O(b3, bRd + off, 3 * 1024);

    asm volatile("s_waitcnt lgkmcnt(0)");
    __builtin_amdgcn_sched_barrier(0);
    __builtin_amdgcn_s_setprio(1);
    acc[0][0] = mfma16(a0, b0, acc[0][0]); acc[0][1] = mfma16(a0, b1, acc[0][1]);
    acc[0][2] = mfma16(a0, b2, acc[0][2]); acc[0][3] = mfma16(a0, b3, acc[0][3]);
    acc[1][0] = mfma16(a1, b0, acc[1][0]); acc[1][1] = mfma16(a1, b1, acc[1][1]);
    acc[1][2] = mfma16(a1, b2, acc[1][2]); acc[1][3] = mfma16(a1, b3, acc[1][3]);
    acc[2][0] = mfma16(a2, b0, acc[2][0]); acc[2][1] = mfma16(a2, b1, acc[2][1]);
    acc[2][2] = mfma16(a2, b2, acc[2][2]); acc[2][3] = mfma16(a2, b3, acc[2][3]);
    acc[3][0] = mfma16(a3, b0, acc[3][0]); acc[3][1] = mfma16(a3, b1, acc[3][1]);
    acc[3][2] = mfma16(a3, b2, acc[3][2]); acc[3][3] = mfma16(a3, b3, acc[3][3]);
    __builtin_amdgcn_s_setprio(0);

    off  = (off  == 32768) ? 0 : off  + 16384;
    soff = (soff == 32768) ? 0 : soff + 16384;
  }

  __syncthreads();  // all waves done; overlay epilogue stripes (4 x 4352B)

  float* eb = (float*)((char*)lds + w * 4352);
  const int erow = lane >> 2, ecol = (lane & 3) * 16;
#pragma unroll
  for (int mf = 0; mf < 4; ++mf) {
#pragma unroll
    for (int nf = 0; nf < 4; ++nf) {
      const int col = bn + wn + nf * 16 + c16;
      const float bsv = bias[col];
#pragma unroll
      for (int j = 0; j < 4; ++j) {
        float v = acc[mf][nf][j] + bsv;
        if constexpr (MODE == 2)
          v = 0.5f * v * (1.0f + erff(v * 0.70710678118654752f));
        eb[(q4 * 4 + j) * 68 + nf * 16 + c16] = v;
      }
    }
    const int gr = bm + wm + mf * 16 + erow;
    const size_t gbase = (size_t)gr * N + bn + wn + ecol;
    unsigned short* cp = (unsigned short*)Cb;
#pragma unroll
    for (int u = 0; u < 2; ++u) {
      float4 a = *(float4*)&eb[erow * 68 + ecol + u * 8];
      float4 b = *(float4*)&eb[erow * 68 + ecol + u * 8 + 4];
      if constexpr (MODE == 3) {
        const float4 ra = *(const float4*)&residf[gbase + u * 8];
        const float4 rb = *(const float4*)&residf[gbase + u * 8 + 4];
        a.x += ra.x; a.y += ra.y; a.z += ra.z; a.w += ra.w;
        b.x += rb.x; b.y += rb.y; b.z += rb.z; b.w += rb.w;
      } else if constexpr (MODE == 4) {
        const u16x8 rv = *(const u16x8*)(residb + gbase + u * 8);
        a.x += bs2f(rv[0]); a.y += bs2f(rv[1]); a.z += bs2f(rv[2]); a.w += bs2f(rv[3]);
        b.x += bs2f(rv[4]); b.y += bs2f(rv[5]); b.z += bs2f(rv[6]); b.w += bs2f(rv[7]);
      }
      u16x8 o;
      o[0] = (unsigned short)f2bs(a.x); o[1] = (unsigned short)f2bs(a.y);
      o[2] = (unsigned short)f2bs(a.z); o[3] = (unsigned short)f2bs(a.w);
      o[4] = (unsigned short)f2bs(b.x); o[5] = (unsigned short)f2bs(b.y);
      o[6] = (unsigned short)f2bs(b.z); o[7] = (unsigned short)f2bs(b.w);
      *(u16x8*)(cp + gbase + u * 8) = o;
    }
  }
}

// per-call-site named wrappers (profiling attribution)
__global__ __launch_bounds__(256)
void gemm_qkv(const short* A, const short* Bt, const float* bias,
              __hip_bfloat16* Cb, int M, int N, int K) {
  gemmr3_body<0>(A, Bt, bias, nullptr, nullptr, Cb, M, N, K);
}
__global__ __launch_bounds__(256)
void gemm_wi(const short* A, const short* Bt, const float* bias,
             __hip_bfloat16* Cb, int M, int N, int K) {
  gemmr3_body<2>(A, Bt, bias, nullptr, nullptr, Cb, M, N, K);
}
__global__ __launch_bounds__(256)
void gemm_wo(const short* A, const short* Bt, const float* bias,
             const float* residf, __hip_bfloat16* Cb, int M, int N, int K) {
  gemmr3_body<3>(A, Bt, bias, residf, nullptr, Cb, M, N, K);
}
__global__ __launch_bounds__(256)
void gemm_wo2(const short* A, const short* Bt, const float* bias,
              const unsigned short* residb, __hip_bfloat16* Cb, int M, int N, int K) {
  gemmr3_body<4>(A, Bt, bias, nullptr, residb, Cb, M, N, K);
}

// ---------------- fused flash attention (unchanged) ----------------

__global__ __launch_bounds__(256)
void attn_flash(const short* __restrict__ Q, const short* __restrict__ Kmat,
                const short* __restrict__ V, const float* __restrict__ mask,
                __hip_bfloat16* __restrict__ ctx, int qs)
{
  __shared__ short Ksm[64 * 64];
  __shared__ short Vsm[64 * 64];
  __shared__ short Psm[4 * 16 * 64];

  const int tid = threadIdx.x;
  const int lane = tid & 63;
  const int w = tid >> 6;
  const int q4 = lane >> 4;
  const int c16 = lane & 15;
  const int b = blockIdx.z;
  const int h = blockIdx.y;
  const int qb = blockIdx.x;

  const size_t rowbase = (size_t)b * 512;
  const int hoff = h * 64;

  bf16x8 aq[2];
  {
    const size_t qrow = rowbase + (size_t)qb * 64 + w * 16 + c16;
    const short* qp = Q + qrow * qs + hoff + q4 * 8;
    aq[0] = *(const bf16x8*)(qp);
    aq[1] = *(const bf16x8*)(qp + 32);
  }

  float m_r[4], l_r[4];
  f32x4 O[4];
#pragma unroll
  for (int j = 0; j < 4; ++j) { m_r[j] = -INFINITY; l_r[j] = 0.f; O[j] = (f32x4){0.f, 0.f, 0.f, 0.f}; }

  const int kc0 = w * 128 + lane;
  const int kp0 = kc0 >> 3, kd0 = (kc0 & 7) * 8;
  const int kc1 = kc0 + 64;
  const int kp1 = kc1 >> 3, kd1 = (kc1 & 7) * 8;

  for (int kv0 = 0; kv0 < 512; kv0 += 64) {
    __syncthreads();
    gload_lds16(Kmat + (rowbase + kv0 + kp0) * qs + hoff + (kd0 ^ ((kp0 & 7) << 3)),
                (char*)Ksm + (size_t)(w * 128 + 0) * 16);
    gload_lds16(Kmat + (rowbase + kv0 + kp1) * qs + hoff + (kd1 ^ ((kp1 & 7) << 3)),
                (char*)Ksm + (size_t)(w * 128 + 64) * 16);
#pragma unroll
    for (int it = 0; it < 2; ++it) {
      const int c = tid + 256 * it;
      const int kp = c >> 3;
      const int dh8 = (c & 7) * 8;
      const bf16x8 vv = *(const bf16x8*)(V + (rowbase + kv0 + kp) * qs + hoff + dh8);
#pragma unroll
      for (int j = 0; j < 8; ++j) {
        const int dh = dh8 + j;
        *(short*)((char*)Vsm + dh * 128 + ((kp * 2) ^ ((dh & 7) << 4))) = vv[j];
      }
    }
    __syncthreads();

    float pv[4][4];
    float mk[4];
#pragma unroll
    for (int t = 0; t < 4; ++t) mk[t] = mask[rowbase + kv0 + t * 16 + c16];
#pragma unroll
    for (int t = 0; t < 4; ++t) {
      f32x4 z = (f32x4){0.f, 0.f, 0.f, 0.f};
      const int kp = t * 16 + c16;
#pragma unroll
      for (int ks = 0; ks < 2; ++ks) {
        const int d = ks * 32 + q4 * 8;
        bf16x8 kf = *(const bf16x8*)((char*)Ksm + kp * 128 + ((d * 2) ^ ((kp & 7) << 4)));
        z = mfma16(aq[ks], kf, z);
      }
#pragma unroll
      for (int j = 0; j < 4; ++j) pv[t][j] = z[j] * 0.125f + mk[t];
    }

#pragma unroll
    for (int j = 0; j < 4; ++j) {
      float mt_ = fmaxf(fmaxf(pv[0][j], pv[1][j]), fmaxf(pv[2][j], pv[3][j]));
#pragma unroll
      for (int o = 8; o >= 1; o >>= 1) mt_ = fmaxf(mt_, __shfl_xor(mt_, o));
      const float mn = fmaxf(m_r[j], mt_);
      const float sc = __expf(m_r[j] - mn);
      float rs = 0.f;
#pragma unroll
      for (int t = 0; t < 4; ++t) { const float pe = __expf(pv[t][j] - mn); pv[t][j] = pe; rs += pe; }
#pragma unroll
      for (int o = 8; o >= 1; o >>= 1) rs += __shfl_xor(rs, o);
      l_r[j] = l_r[j] * sc + rs;
      m_r[j] = mn;
#pragma unroll
      for (int nt = 0; nt < 4; ++nt) O[nt][j] *= sc;
    }

    char* pb = (char*)Psm + w * 2048;
#pragma unroll
    for (int j = 0; j < 4; ++j) {
      const int r = q4 * 4 + j;
#pragma unroll
      for (int t = 0; t < 4; ++t) {
        const int ck = t * 16 + c16;
        *(short*)(pb + r * 128 + ((ck * 2) ^ ((r & 7) << 4))) = f2bs(pv[t][j]);
      }
    }

#pragma unroll
    for (int ks = 0; ks < 2; ++ks) {
      const int kk = ks * 32 + q4 * 8;
      bf16x8 pa = *(const bf16x8*)(pb + c16 * 128 + ((kk * 2) ^ ((c16 & 7) << 4)));
#pragma unroll
      for (int nt = 0; nt < 4; ++nt) {
        const int dh = nt * 16 + c16;
        bf16x8 vf = *(const bf16x8*)((char*)Vsm + dh * 128 + ((kk * 2) ^ ((dh & 7) << 4)));
        O[nt] = mfma16(pa, vf, O[nt]);
      }
    }
  }

  float rinv[4];
#pragma unroll
  for (int j = 0; j < 4; ++j) rinv[j] = 1.0f / l_r[j];
#pragma unroll
  for (int nt = 0; nt < 4; ++nt) {
#pragma unroll
    for (int j = 0; j < 4; ++j) {
      const size_t row = rowbase + (size_t)qb * 64 + w * 16 + q4 * 4 + j;
      ctx[row * 1024 + hoff + nt * 16 + c16] = __float2bfloat16(O[nt][j] * rinv[j]);
    }
  }
}

// ---------------- LayerNorm (bf16 in; bf16 or f32 out; unchanged) ----------------

template<int OUTB>
DEV_INLINE void ln_body(const unsigned short* __restrict__ in, const float* __restrict__ gam,
                        const float* __restrict__ bet, float* __restrict__ outf,
                        unsigned short* __restrict__ outb)
{
  const int row = blockIdx.x;
  const int tid = threadIdx.x;
  const size_t base = (size_t)row * 1024 + tid * 4;
  const ushort4 xi = *(const ushort4*)(in + base);
  const float x0 = bs2f(xi.x), x1 = bs2f(xi.y), x2 = bs2f(xi.z), x3 = bs2f(xi.w);
  float s  = x0 + x1 + x2 + x3;
  float s2 = x0 * x0 + x1 * x1 + x2 * x2 + x3 * x3;
#pragma unroll
  for (int o = 32; o >= 1; o >>= 1) { s += __shfl_xor(s, o); s2 += __shfl_xor(s2, o); }
  __shared__ float sb[8];
  const int w = tid >> 6;
  if ((tid & 63) == 0) { sb[w] = s; sb[w + 4] = s2; }
  __syncthreads();
  const float ts  = sb[0] + sb[1] + sb[2] + sb[3];
  const float ts2 = sb[4] + sb[5] + sb[6] + sb[7];
  const float mu = ts * (1.0f / 1024.0f);
  const float var = ts2 * (1.0f / 1024.0f) - mu * mu;
  const float rstd = rsqrtf(var + 1e-12f);
  const float4 g4 = *(const float4*)(gam + tid * 4);
  const float4 b4 = *(const float4*)(bet + tid * 4);
  const float y0 = (x0 - mu) * rstd * g4.x + b4.x;
  const float y1 = (x1 - mu) * rstd * g4.y + b4.y;
  const float y2 = (x2 - mu) * rstd * g4.z + b4.z;
  const float y3 = (x3 - mu) * rstd * g4.w + b4.w;
  if constexpr (OUTB) {
    ushort4 o;
    o.x = (unsigned short)f2bs(y0); o.y = (unsigned short)f2bs(y1);
    o.z = (unsigned short)f2bs(y2); o.w = (unsigned short)f2bs(y3);
    *(ushort4*)(outb + base) = o;
  } else {
    float4 y; y.x = y0; y.y = y1; y.z = y2; y.w = y3;
    *(float4*)(outf + base) = y;
  }
}

__global__ __launch_bounds__(256)
void ln_attn(const unsigned short* in, const float* gam, const float* bet,
             unsigned short* outb) { ln_body<1>(in, gam, bet, nullptr, outb); }
__global__ __launch_bounds__(256)
void ln_ffn(const unsigned short* in, const float* gam, const float* bet, float* outf) {
  ln_body<0>(in, gam, bet, outf, nullptr);
}

// ---------------- launch ----------------

extern "C" void kernel_launch(void* const* d_in, const int* in_sizes, int n_in,
                              void* d_out, int out_size, void* d_ws, size_t ws_size,
                              hipStream_t stream)
{
  const float* X    = (const float*)d_in[0];
  const float* mask = (const float*)d_in[1];
  const float* Wq   = (const float*)d_in[2];   const float* bq  = (const float*)d_in[3];
  const float* Wk   = (const float*)d_in[4];   const float* bk  = (const float*)d_in[5];
  const float* Wv   = (const float*)d_in[6];   const float* bv  = (const float*)d_in[7];
  const float* Wo   = (const float*)d_in[8];   const float* bo  = (const float*)d_in[9];
  const float* g1   = (const float*)d_in[10];  const float* b1  = (const float*)d_in[11];
  const float* Wi   = (const float*)d_in[12];  const float* bi  = (const float*)d_in[13];
  const float* Wo2  = (const float*)d_in[14];  const float* bo2 = (const float*)d_in[15];
  const float* g2   = (const float*)d_in[16];  const float* b2  = (const float*)d_in[17];
  float* out = (float*)d_out;
  (void)in_sizes; (void)n_in; (void)out_size; (void)ws_size;

  const size_t D = 1024, F = 4096;
  const size_t MN = 8192 * D;

  char* p = (char*)d_ws;
  auto alloc = [&](size_t bytes) { char* r = p; p += (bytes + 255) & ~(size_t)255; return r; };
  short* Xb    = (short*)alloc(MN * 2);            // bf16 X -> ctx -> pre-LN2
  short* QKVb  = (short*)alloc(8192 * 3072 * 2);   // QKV -> LN1 out (A for Wi, resid for Wo2)
  short* WqkvT = (short*)alloc(3072 * D * 2);
  short* WoT   = (short*)alloc(D * D * 2);
  short* WiT   = (short*)alloc(D * F * 2);
  short* Wo2T  = (short*)alloc(D * F * 2);
  float* bqkv  = (float*)alloc(3072 * 4);
  short* I1    = (short*)alloc(8192 * F * 2);      // gelu intermediate

  // --- fused prep ---
  prep_all<<<dim3(20484), 256, 0, stream>>>(X, (__hip_bfloat16*)Xb,
                                            Wq, Wk, Wv, Wo, Wi, Wo2,
                                            (__hip_bfloat16*)WqkvT, (__hip_bfloat16*)WoT,
                                            (__hip_bfloat16*)WiT, (__hip_bfloat16*)Wo2T,
                                            bq, bk, bv, bqkv);

  // --- QKV projection ---
  gemm_qkv<<<dim3(1536), 256, 0, stream>>>(Xb, WqkvT, bqkv, (__hip_bfloat16*)QKVb, 8192, 3072, 1024);

  // --- fused attention (ctx overwrites Xb) ---
  attn_flash<<<dim3(8, 16, 16), 256, 0, stream>>>(QKVb, QKVb + 1024, QKVb + 2048, mask,
                                                  (__hip_bfloat16*)Xb, 3072);

  // --- self-output dense + residual -> bf16 pre-LN1 (d_out scratch), LN1 -> bf16 QKVb ---
  gemm_wo<<<dim3(512), 256, 0, stream>>>(Xb, WoT, bo, X, (__hip_bfloat16*)out, 8192, 1024, 1024);
  ln_attn<<<dim3(8192), 256, 0, stream>>>((const unsigned short*)out, g1, b1, (unsigned short*)QKVb);

  // --- intermediate dense + gelu ---
  gemm_wi<<<dim3(2048), 256, 0, stream>>>(QKVb, WiT, bi, (__hip_bfloat16*)I1, 8192, 4096, 1024);

  // --- output dense + bf16 residual -> bf16 pre-LN2 (Xb), LN2 -> f32 d_out ---
  gemm_wo2<<<dim3(512), 256, 0, stream>>>(I1, Wo2T, bo2, (const unsigned short*)QKVb,
                                          (__hip_bfloat16*)Xb, 8192, 1024, 4096);
  ln_ffn<<<dim3(8192), 256, 0, stream>>>((const unsigned short*)Xb, g2, b2, out);
}

// Round 13
// 356.908 us; speedup vs baseline: 1.1173x; 1.1173x over previous
//
#include <hip/hip_runtime.h>
#include <hip/hip_bf16.h>
#include <math.h>

#define DEV_INLINE __device__ __forceinline__

typedef __attribute__((ext_vector_type(8))) short bf16x8;
typedef __attribute__((ext_vector_type(8))) unsigned short u16x8;
typedef __attribute__((ext_vector_type(4))) float f32x4;

// ---------------- helpers ----------------

DEV_INLINE void gload_lds16(const void* g, void* l) {
  __builtin_amdgcn_global_load_lds(
      (__attribute__((address_space(1))) unsigned int*)const_cast<void*>(g),
      (__attribute__((address_space(3))) unsigned int*)l,
      16, 0, 0);
}

DEV_INLINE unsigned lds_a(const void* p) {
  return (unsigned)(unsigned long long)(__attribute__((address_space(3))) const void*)p;
}

DEV_INLINE short f2bs(float x) {
  union { __hip_bfloat16 h; short s; } u;
  u.h = __float2bfloat16(x);
  return u.s;
}

DEV_INLINE float bs2f(unsigned short s) {
  union { float f; unsigned u; } v;
  v.u = ((unsigned)s) << 16;
  return v.f;
}

DEV_INLINE f32x4 mfma16(bf16x8 a, bf16x8 b, f32x4 c) {
  return __builtin_amdgcn_mfma_f32_16x16x32_bf16(a, b, c, 0, 0, 0);
}

#define DSREAD_O(dst, base, imm) \
  asm volatile("ds_read_b128 %0, %1 offset:%2" : "=v"(dst) : "v"(base), "n"(imm))

// ---------------- fused prep kernel: X-convert + 6 transposes + bias concat ----------------

__global__ __launch_bounds__(256)
void prep_all(const float* __restrict__ X, __hip_bfloat16* __restrict__ Xb,
              const float* __restrict__ Wq, const float* __restrict__ Wk,
              const float* __restrict__ Wv, const float* __restrict__ Wo,
              const float* __restrict__ Wi, const float* __restrict__ Wo2,
              __hip_bfloat16* __restrict__ WqkvT, __hip_bfloat16* __restrict__ WoT,
              __hip_bfloat16* __restrict__ WiT, __hip_bfloat16* __restrict__ Wo2T,
              const float* __restrict__ bq, const float* __restrict__ bk,
              const float* __restrict__ bv, float* __restrict__ bqkv)
{
  int bx = blockIdx.x;
  const int tid = threadIdx.x;

  if (bx < 8192) {  // X f32 -> bf16
    const size_t i = ((size_t)bx * 256 + tid) * 4;
    const float4 x = *(const float4*)(X + i);
    union { __hip_bfloat16 h[4]; ushort4 u; } pk;
    pk.h[0] = __float2bfloat16(x.x);
    pk.h[1] = __float2bfloat16(x.y);
    pk.h[2] = __float2bfloat16(x.z);
    pk.h[3] = __float2bfloat16(x.w);
    *(ushort4*)(Xb + i) = pk.u;
    return;
  }
  bx -= 8192;
  if (bx < 4) {  // bias concat
    const int i = bx * 256 + tid;
    bqkv[i] = bq[i]; bqkv[1024 + i] = bk[i]; bqkv[2048 + i] = bv[i];
    return;
  }
  bx -= 4;

  const float* Wsrc; __hip_bfloat16* Wdst; int K, N, nt, kt;
  if (bx < 1024)      { Wsrc = Wq;  Wdst = WqkvT;               K = 1024; N = 1024; nt = bx & 31;  kt = bx >> 5; }
  else if (bx < 2048) { const int l = bx - 1024; Wsrc = Wk;  Wdst = WqkvT + 1024 * 1024; K = 1024; N = 1024; nt = l & 31;  kt = l >> 5; }
  else if (bx < 3072) { const int l = bx - 2048; Wsrc = Wv;  Wdst = WqkvT + 2048 * 1024; K = 1024; N = 1024; nt = l & 31;  kt = l >> 5; }
  else if (bx < 4096) { const int l = bx - 3072; Wsrc = Wo;  Wdst = WoT;  K = 1024; N = 1024; nt = l & 31;  kt = l >> 5; }
  else if (bx < 8192) { const int l = bx - 4096; Wsrc = Wi;  Wdst = WiT;  K = 1024; N = 4096; nt = l & 127; kt = l >> 7; }
  else                { const int l = bx - 8192; Wsrc = Wo2; Wdst = Wo2T; K = 4096; N = 1024; nt = l & 31;  kt = l >> 5; }

  __shared__ float t[32][33];
  const int n0 = nt * 32, k0 = kt * 32;
  const int tx = tid & 31, ty = tid >> 5;
#pragma unroll
  for (int r = ty; r < 32; r += 8)
    t[r][tx] = Wsrc[(size_t)(k0 + r) * N + n0 + tx];
  __syncthreads();
#pragma unroll
  for (int r = ty; r < 32; r += 8)
    Wdst[(size_t)(n0 + r) * K + k0 + tx] = __float2bfloat16(t[tx][r]);
}

// ====== 256x128 single-buffered GEMM (big-N ops): C = A @ Bt^T ======
// L2-locality superblocking: 4bm x 8bn blocks per superblock; superblocks
// contiguous per XCD (B panel stays L2-resident across the XCD's pass).
// MODE 0: bf16(acc+bias); 2: bf16(gelu(acc+bias))

template<int MODE>
DEV_INLINE void gemm256_body(const short* __restrict__ A, const short* __restrict__ Bt,
                             const float* __restrict__ bias,
                             __hip_bfloat16* __restrict__ Cb,
                             int M, int N, int K)
{
  __shared__ __align__(128) short lds[24576];   // 48KB: A [0,32K)B, B [32K,48K)B

  const int tid = threadIdx.x;
  const int lane = tid & 63, wid = tid >> 6;
  const int q4 = lane >> 4, c16 = lane & 15;
  const int wm = (wid >> 1) * 64, wn = (wid & 1) * 64;

  // superblocked XCD-aware block mapping (grid = nMT*nNT; (grid/8)%32 == 0)
  int bm, bn;
  {
    const int nMT = M >> 8;            // 256-row tiles
    const int nSBm = nMT >> 2;         // superblock rows (4 bm each)
    const int xcd = blockIdx.x & 7;
    const int i = blockIdx.x >> 3;     // index within XCD
    const int nSBx = (int)gridDim.x >> 8;  // superblocks per XCD
    const int S = xcd * nSBx + (i >> 5);   // global superblock id
    const int within = i & 31;             // 4x8 within superblock
    bm = ((S % nSBm) * 4 + (within >> 3)) * 256;
    bn = ((S / nSBm) * 8 + (within & 7)) * 128;
  }

  const int sr = tid >> 3, sl = tid & 7;
  const int sg = (sl ^ (sr & 7)) * 8;
  const short* pA = A  + (size_t)(bm + sr) * K + sg;
  const short* pB = Bt + (size_t)(bn + sr) * K + sg;
  char* const baseA = (char*)lds;
  char* const baseB = (char*)lds + 32768;

  f32x4 acc[4][4];
#pragma unroll
  for (int i = 0; i < 4; ++i)
#pragma unroll
    for (int j = 0; j < 4; ++j) acc[i][j] = (f32x4){0.f, 0.f, 0.f, 0.f};

  for (int kt = 0; kt < K; kt += 64) {
    __syncthreads();
#pragma unroll
    for (int u = 0; u < 4; ++u)
      gload_lds16(pA + (size_t)u * 64 * K + kt, baseA + u * 8192 + wid * 1024);
#pragma unroll
    for (int u = 0; u < 2; ++u)
      gload_lds16(pB + (size_t)u * 64 * K + kt, baseB + u * 8192 + wid * 1024);
    __syncthreads();

#pragma unroll
    for (int kk = 0; kk < 2; ++kk) {
      bf16x8 af[4], bfr[4];
#pragma unroll
      for (int mt = 0; mt < 4; ++mt)
        af[mt] = *(const bf16x8*)(baseA + (wm + mt * 16 + c16) * 128 +
                                  (((kk * 4 + q4) ^ (c16 & 7)) * 16));
#pragma unroll
      for (int nt = 0; nt < 4; ++nt)
        bfr[nt] = *(const bf16x8*)(baseB + (wn + nt * 16 + c16) * 128 +
                                   (((kk * 4 + q4) ^ (c16 & 7)) * 16));
#pragma unroll
      for (int mt = 0; mt < 4; ++mt)
#pragma unroll
        for (int nt = 0; nt < 4; ++nt)
          acc[mt][nt] = mfma16(af[mt], bfr[nt], acc[mt][nt]);
    }
  }

  __syncthreads();  // staging dead; overlay epilogue stripes

  float* eb = (float*)((char*)lds + wid * 4352);
  const int erow = lane >> 2, ecol = (lane & 3) * 16;
#pragma unroll
  for (int mf = 0; mf < 4; ++mf) {
#pragma unroll
    for (int nf = 0; nf < 4; ++nf) {
      const int col = bn + wn + nf * 16 + c16;
      const float bsv = bias[col];
#pragma unroll
      for (int j = 0; j < 4; ++j) {
        float v = acc[mf][nf][j] + bsv;
        if constexpr (MODE == 2)
          v = 0.5f * v * (1.0f + erff(v * 0.70710678118654752f));
        eb[(q4 * 4 + j) * 68 + nf * 16 + c16] = v;
      }
    }
    const int gr = bm + wm + mf * 16 + erow;
    const size_t gbase = (size_t)gr * N + bn + wn + ecol;
    unsigned short* cp = (unsigned short*)Cb;
#pragma unroll
    for (int u = 0; u < 2; ++u) {
      float4 a = *(float4*)&eb[erow * 68 + ecol + u * 8];
      float4 b = *(float4*)&eb[erow * 68 + ecol + u * 8 + 4];
      u16x8 o;
      o[0] = (unsigned short)f2bs(a.x); o[1] = (unsigned short)f2bs(a.y);
      o[2] = (unsigned short)f2bs(a.z); o[3] = (unsigned short)f2bs(a.w);
      o[4] = (unsigned short)f2bs(b.x); o[5] = (unsigned short)f2bs(b.y);
      o[6] = (unsigned short)f2bs(b.z); o[7] = (unsigned short)f2bs(b.w);
      *(u16x8*)(cp + gbase + u * 8) = o;
    }
  }
}

// ====== 2-phase dbuf 128x128 GEMM (N=1024 ops) ======
// MODE 3: bf16(acc + bias + f32 resid); MODE 4: bf16(acc + bias + bf16 resid)

template<int MODE>
DEV_INLINE void gemm64_body(const short* __restrict__ A, const short* __restrict__ Bt,
                            const float* __restrict__ bias,
                            const float* __restrict__ residf,
                            const unsigned short* __restrict__ residb,
                            __hip_bfloat16* __restrict__ Cb,
                            int M, int N, int K)
{
  __shared__ __align__(128) short lds[32768];   // 64KB: two 32KB buffers

  const int tid = threadIdx.x;
  const int lane = tid & 63, w = tid >> 6;
  const int q4 = lane >> 4, c16 = lane & 15;
  const int wm = (w >> 1) * 64, wn = (w & 1) * 64;

  const int nNT = N >> 7;
  int bid = blockIdx.x;
  { const int cpx = (int)gridDim.x >> 3; bid = (bid & 7) * cpx + (bid >> 3); }
  const int bm = (bid / nNT) * 128;
  const int bn = (bid % nNT) * 128;

  const int sr = tid >> 3, sl = tid & 7;
  const int sg = (sl ^ (sr & 7)) * 8;
  const short* pA = A  + (size_t)(bm + sr) * K + sg;
  const short* pB = Bt + (size_t)(bn + sr) * K + sg;

  const int s0 = (q4 ^ (c16 & 7)) * 16;
  const int s1 = ((q4 ^ 4) ^ (c16 & 7)) * 16;
  unsigned aRd0 = lds_a(lds) + (unsigned)((wm + c16) * 128 + s0);
  unsigned aRd1 = lds_a(lds) + (unsigned)((wm + c16) * 128 + s1);
  unsigned bRd0 = lds_a(lds) + (unsigned)(16384 + (wn + c16) * 128 + s0);
  unsigned bRd1 = lds_a(lds) + (unsigned)(16384 + (wn + c16) * 128 + s1);

  f32x4 acc[4][4];
#pragma unroll
  for (int i = 0; i < 4; ++i)
#pragma unroll
    for (int j = 0; j < 4; ++j) acc[i][j] = (f32x4){0.f, 0.f, 0.f, 0.f};

  auto stage = [&](int buf, int kt) {
    char* b = (char*)lds + buf * 32768;
#pragma unroll
    for (int u = 0; u < 4; ++u) {
      gload_lds16(pA + (size_t)u * 32 * K + kt, b + u * 4096 + w * 1024);
      gload_lds16(pB + (size_t)u * 32 * K + kt, b + 16384 + u * 4096 + w * 1024);
    }
  };

  stage(0, 0);
  __syncthreads();

  const int NT = K >> 6;
  int cur = 0;
  for (int t = 0; t < NT; ++t) {
    __builtin_amdgcn_sched_barrier(0);
    if (t + 1 < NT) stage(cur ^ 1, (t + 1) << 6);
    __builtin_amdgcn_sched_barrier(0);

    bf16x8 a0, a1, a2, a3, a4, a5, a6, a7;
    bf16x8 b0, b1, b2, b3, b4, b5, b6, b7;
    DSREAD_O(a0, aRd0, 0 * 2048); DSREAD_O(a1, aRd0, 1 * 2048);
    DSREAD_O(a2, aRd0, 2 * 2048); DSREAD_O(a3, aRd0, 3 * 2048);
    DSREAD_O(b0, bRd0, 0 * 2048); DSREAD_O(b1, bRd0, 1 * 2048);
    DSREAD_O(b2, bRd0, 2 * 2048); DSREAD_O(b3, bRd0, 3 * 2048);
    DSREAD_O(a4, aRd1, 0 * 2048); DSREAD_O(a5, aRd1, 1 * 2048);
    DSREAD_O(a6, aRd1, 2 * 2048); DSREAD_O(a7, aRd1, 3 * 2048);
    DSREAD_O(b4, bRd1, 0 * 2048); DSREAD_O(b5, bRd1, 1 * 2048);
    DSREAD_O(b6, bRd1, 2 * 2048); DSREAD_O(b7, bRd1, 3 * 2048);

    asm volatile("s_waitcnt lgkmcnt(0)");
    __builtin_amdgcn_sched_barrier(0);
    __builtin_amdgcn_s_setprio(1);
    acc[0][0] = mfma16(a0, b0, acc[0][0]); acc[0][1] = mfma16(a0, b1, acc[0][1]);
    acc[0][2] = mfma16(a0, b2, acc[0][2]); acc[0][3] = mfma16(a0, b3, acc[0][3]);
    acc[1][0] = mfma16(a1, b0, acc[1][0]); acc[1][1] = mfma16(a1, b1, acc[1][1]);
    acc[1][2] = mfma16(a1, b2, acc[1][2]); acc[1][3] = mfma16(a1, b3, acc[1][3]);
    acc[2][0] = mfma16(a2, b0, acc[2][0]); acc[2][1] = mfma16(a2, b1, acc[2][1]);
    acc[2][2] = mfma16(a2, b2, acc[2][2]); acc[2][3] = mfma16(a2, b3, acc[2][3]);
    acc[3][0] = mfma16(a3, b0, acc[3][0]); acc[3][1] = mfma16(a3, b1, acc[3][1]);
    acc[3][2] = mfma16(a3, b2, acc[3][2]); acc[3][3] = mfma16(a3, b3, acc[3][3]);
    acc[0][0] = mfma16(a4, b4, acc[0][0]); acc[0][1] = mfma16(a4, b5, acc[0][1]);
    acc[0][2] = mfma16(a4, b6, acc[0][2]); acc[0][3] = mfma16(a4, b7, acc[0][3]);
    acc[1][0] = mfma16(a5, b4, acc[1][0]); acc[1][1] = mfma16(a5, b5, acc[1][1]);
    acc[1][2] = mfma16(a5, b6, acc[1][2]); acc[1][3] = mfma16(a5, b7, acc[1][3]);
    acc[2][0] = mfma16(a6, b4, acc[2][0]); acc[2][1] = mfma16(a6, b5, acc[2][1]);
    acc[2][2] = mfma16(a6, b6, acc[2][2]); acc[2][3] = mfma16(a6, b7, acc[2][3]);
    acc[3][0] = mfma16(a7, b4, acc[3][0]); acc[3][1] = mfma16(a7, b5, acc[3][1]);
    acc[3][2] = mfma16(a7, b6, acc[3][2]); acc[3][3] = mfma16(a7, b7, acc[3][3]);
    __builtin_amdgcn_s_setprio(0);

    __syncthreads();
    aRd0 ^= 0x8000; aRd1 ^= 0x8000; bRd0 ^= 0x8000; bRd1 ^= 0x8000; cur ^= 1;
  }

  float* eb = (float*)((char*)lds + w * 4352);
  const int erow = lane >> 2, ecol = (lane & 3) * 16;
#pragma unroll
  for (int mf = 0; mf < 4; ++mf) {
#pragma unroll
    for (int nf = 0; nf < 4; ++nf) {
      const int col = bn + wn + nf * 16 + c16;
      const float bsv = bias[col];
#pragma unroll
      for (int j = 0; j < 4; ++j)
        eb[(q4 * 4 + j) * 68 + nf * 16 + c16] = acc[mf][nf][j] + bsv;
    }
    const int gr = bm + wm + mf * 16 + erow;
    const size_t gbase = (size_t)gr * N + bn + wn + ecol;
    unsigned short* cp = (unsigned short*)Cb;
#pragma unroll
    for (int u = 0; u < 2; ++u) {
      float4 a = *(float4*)&eb[erow * 68 + ecol + u * 8];
      float4 b = *(float4*)&eb[erow * 68 + ecol + u * 8 + 4];
      if constexpr (MODE == 3) {
        const float4 ra = *(const float4*)&residf[gbase + u * 8];
        const float4 rb = *(const float4*)&residf[gbase + u * 8 + 4];
        a.x += ra.x; a.y += ra.y; a.z += ra.z; a.w += ra.w;
        b.x += rb.x; b.y += rb.y; b.z += rb.z; b.w += rb.w;
      } else {
        const u16x8 rv = *(const u16x8*)(residb + gbase + u * 8);
        a.x += bs2f(rv[0]); a.y += bs2f(rv[1]); a.z += bs2f(rv[2]); a.w += bs2f(rv[3]);
        b.x += bs2f(rv[4]); b.y += bs2f(rv[5]); b.z += bs2f(rv[6]); b.w += bs2f(rv[7]);
      }
      u16x8 o;
      o[0] = (unsigned short)f2bs(a.x); o[1] = (unsigned short)f2bs(a.y);
      o[2] = (unsigned short)f2bs(a.z); o[3] = (unsigned short)f2bs(a.w);
      o[4] = (unsigned short)f2bs(b.x); o[5] = (unsigned short)f2bs(b.y);
      o[6] = (unsigned short)f2bs(b.z); o[7] = (unsigned short)f2bs(b.w);
      *(u16x8*)(cp + gbase + u * 8) = o;
    }
  }
}

// per-call-site named wrappers (profiling attribution)
__global__ __launch_bounds__(512)
void gemm_qkv(const short* A, const short* Bt, const float* bias,
              __hip_bfloat16* Cb, int M, int N, int K) {
  gemm256_body<0>(A, Bt, bias, Cb, M, N, K);
}
__global__ __launch_bounds__(512)
void gemm_wi(const short* A, const short* Bt, const float* bias,
             __hip_bfloat16* Cb, int M, int N, int K) {
  gemm256_body<2>(A, Bt, bias, Cb, M, N, K);
}
__global__ __launch_bounds__(256)
void gemm_wo(const short* A, const short* Bt, const float* bias,
             const float* residf, __hip_bfloat16* Cb, int M, int N, int K) {
  gemm64_body<3>(A, Bt, bias, residf, nullptr, Cb, M, N, K);
}
__global__ __launch_bounds__(256)
void gemm_wo2(const short* A, const short* Bt, const float* bias,
              const unsigned short* residb, __hip_bfloat16* Cb, int M, int N, int K) {
  gemm64_body<4>(A, Bt, bias, nullptr, residb, Cb, M, N, K);
}

// ---------------- fused flash attention ----------------

__global__ __launch_bounds__(256)
void attn_flash(const short* __restrict__ Q, const short* __restrict__ Kmat,
                const short* __restrict__ V, const float* __restrict__ mask,
                __hip_bfloat16* __restrict__ ctx, int qs)
{
  __shared__ short Ksm[64 * 64];
  __shared__ short Vsm[64 * 64];
  __shared__ short Psm[4 * 16 * 64];

  const int tid = threadIdx.x;
  const int lane = tid & 63;
  const int w = tid >> 6;
  const int q4 = lane >> 4;
  const int c16 = lane & 15;
  const int b = blockIdx.z;
  const int h = blockIdx.y;
  const int qb = blockIdx.x;

  const size_t rowbase = (size_t)b * 512;
  const int hoff = h * 64;

  bf16x8 aq[2];
  {
    const size_t qrow = rowbase + (size_t)qb * 64 + w * 16 + c16;
    const short* qp = Q + qrow * qs + hoff + q4 * 8;
    aq[0] = *(const bf16x8*)(qp);
    aq[1] = *(const bf16x8*)(qp + 32);
  }

  float m_r[4], l_r[4];
  f32x4 O[4];
#pragma unroll
  for (int j = 0; j < 4; ++j) { m_r[j] = -INFINITY; l_r[j] = 0.f; O[j] = (f32x4){0.f, 0.f, 0.f, 0.f}; }

  const int kc0 = w * 128 + lane;
  const int kp0 = kc0 >> 3, kd0 = (kc0 & 7) * 8;
  const int kc1 = kc0 + 64;
  const int kp1 = kc1 >> 3, kd1 = (kc1 & 7) * 8;

  for (int kv0 = 0; kv0 < 512; kv0 += 64) {
    __syncthreads();
    gload_lds16(Kmat + (rowbase + kv0 + kp0) * qs + hoff + (kd0 ^ ((kp0 & 7) << 3)),
                (char*)Ksm + (size_t)(w * 128 + 0) * 16);
    gload_lds16(Kmat + (rowbase + kv0 + kp1) * qs + hoff + (kd1 ^ ((kp1 & 7) << 3)),
                (char*)Ksm + (size_t)(w * 128 + 64) * 16);
#pragma unroll
    for (int it = 0; it < 2; ++it) {
      const int c = tid + 256 * it;
      const int kp = c >> 3;
      const int dh8 = (c & 7) * 8;
      const bf16x8 vv = *(const bf16x8*)(V + (rowbase + kv0 + kp) * qs + hoff + dh8);
#pragma unroll
      for (int j = 0; j < 8; ++j) {
        const int dh = dh8 + j;
        *(short*)((char*)Vsm + dh * 128 + ((kp * 2) ^ ((dh & 7) << 4))) = vv[j];
      }
    }
    __syncthreads();

    float pv[4][4];
    float mk[4];
#pragma unroll
    for (int t = 0; t < 4; ++t) mk[t] = mask[rowbase + kv0 + t * 16 + c16];
#pragma unroll
    for (int t = 0; t < 4; ++t) {
      f32x4 z = (f32x4){0.f, 0.f, 0.f, 0.f};
      const int kp = t * 16 + c16;
#pragma unroll
      for (int ks = 0; ks < 2; ++ks) {
        const int d = ks * 32 + q4 * 8;
        bf16x8 kf = *(const bf16x8*)((char*)Ksm + kp * 128 + ((d * 2) ^ ((kp & 7) << 4)));
        z = mfma16(aq[ks], kf, z);
      }
#pragma unroll
      for (int j = 0; j < 4; ++j) pv[t][j] = z[j] * 0.125f + mk[t];
    }

#pragma unroll
    for (int j = 0; j < 4; ++j) {
      float mt_ = fmaxf(fmaxf(pv[0][j], pv[1][j]), fmaxf(pv[2][j], pv[3][j]));
#pragma unroll
      for (int o = 8; o >= 1; o >>= 1) mt_ = fmaxf(mt_, __shfl_xor(mt_, o));
      const float mn = fmaxf(m_r[j], mt_);
      const float sc = __expf(m_r[j] - mn);
      float rs = 0.f;
#pragma unroll
      for (int t = 0; t < 4; ++t) { const float pe = __expf(pv[t][j] - mn); pv[t][j] = pe; rs += pe; }
#pragma unroll
      for (int o = 8; o >= 1; o >>= 1) rs += __shfl_xor(rs, o);
      l_r[j] = l_r[j] * sc + rs;
      m_r[j] = mn;
#pragma unroll
      for (int nt = 0; nt < 4; ++nt) O[nt][j] *= sc;
    }

    char* pb = (char*)Psm + w * 2048;
#pragma unroll
    for (int j = 0; j < 4; ++j) {
      const int r = q4 * 4 + j;
#pragma unroll
      for (int t = 0; t < 4; ++t) {
        const int ck = t * 16 + c16;
        *(short*)(pb + r * 128 + ((ck * 2) ^ ((r & 7) << 4))) = f2bs(pv[t][j]);
      }
    }

#pragma unroll
    for (int ks = 0; ks < 2; ++ks) {
      const int kk = ks * 32 + q4 * 8;
      bf16x8 pa = *(const bf16x8*)(pb + c16 * 128 + ((kk * 2) ^ ((c16 & 7) << 4)));
#pragma unroll
      for (int nt = 0; nt < 4; ++nt) {
        const int dh = nt * 16 + c16;
        bf16x8 vf = *(const bf16x8*)((char*)Vsm + dh * 128 + ((kk * 2) ^ ((dh & 7) << 4)));
        O[nt] = mfma16(pa, vf, O[nt]);
      }
    }
  }

  float rinv[4];
#pragma unroll
  for (int j = 0; j < 4; ++j) rinv[j] = 1.0f / l_r[j];
#pragma unroll
  for (int nt = 0; nt < 4; ++nt) {
#pragma unroll
    for (int j = 0; j < 4; ++j) {
      const size_t row = rowbase + (size_t)qb * 64 + w * 16 + q4 * 4 + j;
      ctx[row * 1024 + hoff + nt * 16 + c16] = __float2bfloat16(O[nt][j] * rinv[j]);
    }
  }
}

// ---------------- LayerNorm (bf16 in; bf16 or f32 out) ----------------

template<int OUTB>
DEV_INLINE void ln_body(const unsigned short* __restrict__ in, const float* __restrict__ gam,
                        const float* __restrict__ bet, float* __restrict__ outf,
                        unsigned short* __restrict__ outb)
{
  const int row = blockIdx.x;
  const int tid = threadIdx.x;
  const size_t base = (size_t)row * 1024 + tid * 4;
  const ushort4 xi = *(const ushort4*)(in + base);
  const float x0 = bs2f(xi.x), x1 = bs2f(xi.y), x2 = bs2f(xi.z), x3 = bs2f(xi.w);
  float s  = x0 + x1 + x2 + x3;
  float s2 = x0 * x0 + x1 * x1 + x2 * x2 + x3 * x3;
#pragma unroll
  for (int o = 32; o >= 1; o >>= 1) { s += __shfl_xor(s, o); s2 += __shfl_xor(s2, o); }
  __shared__ float sb[8];
  const int w = tid >> 6;
  if ((tid & 63) == 0) { sb[w] = s; sb[w + 4] = s2; }
  __syncthreads();
  const float ts  = sb[0] + sb[1] + sb[2] + sb[3];
  const float ts2 = sb[4] + sb[5] + sb[6] + sb[7];
  const float mu = ts * (1.0f / 1024.0f);
  const float var = ts2 * (1.0f / 1024.0f) - mu * mu;
  const float rstd = rsqrtf(var + 1e-12f);
  const float4 g4 = *(const float4*)(gam + tid * 4);
  const float4 b4 = *(const float4*)(bet + tid * 4);
  const float y0 = (x0 - mu) * rstd * g4.x + b4.x;
  const float y1 = (x1 - mu) * rstd * g4.y + b4.y;
  const float y2 = (x2 - mu) * rstd * g4.z + b4.z;
  const float y3 = (x3 - mu) * rstd * g4.w + b4.w;
  if constexpr (OUTB) {
    ushort4 o;
    o.x = (unsigned short)f2bs(y0); o.y = (unsigned short)f2bs(y1);
    o.z = (unsigned short)f2bs(y2); o.w = (unsigned short)f2bs(y3);
    *(ushort4*)(outb + base) = o;
  } else {
    float4 y; y.x = y0; y.y = y1; y.z = y2; y.w = y3;
    *(float4*)(outf + base) = y;
  }
}

__global__ __launch_bounds__(256)
void ln_attn(const unsigned short* in, const float* gam, const float* bet,
             unsigned short* outb) { ln_body<1>(in, gam, bet, nullptr, outb); }
__global__ __launch_bounds__(256)
void ln_ffn(const unsigned short* in, const float* gam, const float* bet, float* outf) {
  ln_body<0>(in, gam, bet, outf, nullptr);
}

// ---------------- launch ----------------

extern "C" void kernel_launch(void* const* d_in, const int* in_sizes, int n_in,
                              void* d_out, int out_size, void* d_ws, size_t ws_size,
                              hipStream_t stream)
{
  const float* X    = (const float*)d_in[0];
  const float* mask = (const float*)d_in[1];
  const float* Wq   = (const float*)d_in[2];   const float* bq  = (const float*)d_in[3];
  const float* Wk   = (const float*)d_in[4];   const float* bk  = (const float*)d_in[5];
  const float* Wv   = (const float*)d_in[6];   const float* bv  = (const float*)d_in[7];
  const float* Wo   = (const float*)d_in[8];   const float* bo  = (const float*)d_in[9];
  const float* g1   = (const float*)d_in[10];  const float* b1  = (const float*)d_in[11];
  const float* Wi   = (const float*)d_in[12];  const float* bi  = (const float*)d_in[13];
  const float* Wo2  = (const float*)d_in[14];  const float* bo2 = (const float*)d_in[15];
  const float* g2   = (const float*)d_in[16];  const float* b2  = (const float*)d_in[17];
  float* out = (float*)d_out;
  (void)in_sizes; (void)n_in; (void)out_size; (void)ws_size;

  const size_t D = 1024, F = 4096;
  const size_t MN = 8192 * D;

  char* p = (char*)d_ws;
  auto alloc = [&](size_t bytes) { char* r = p; p += (bytes + 255) & ~(size_t)255; return r; };
  short* Xb    = (short*)alloc(MN * 2);            // bf16 X -> ctx -> pre-LN2
  short* QKVb  = (short*)alloc(8192 * 3072 * 2);   // QKV -> LN1 out (A for Wi, resid for Wo2)
  short* WqkvT = (short*)alloc(3072 * D * 2);
  short* WoT   = (short*)alloc(D * D * 2);
  short* WiT   = (short*)alloc(D * F * 2);
  short* Wo2T  = (short*)alloc(D * F * 2);
  float* bqkv  = (float*)alloc(3072 * 4);
  short* I1    = (short*)alloc(8192 * F * 2);      // gelu intermediate

  // --- fused prep: X convert + weight transposes + bias concat (1 launch) ---
  prep_all<<<dim3(20484), 256, 0, stream>>>(X, (__hip_bfloat16*)Xb,
                                            Wq, Wk, Wv, Wo, Wi, Wo2,
                                            (__hip_bfloat16*)WqkvT, (__hip_bfloat16*)WoT,
                                            (__hip_bfloat16*)WiT, (__hip_bfloat16*)Wo2T,
                                            bq, bk, bv, bqkv);

  // --- QKV projection ---
  gemm_qkv<<<dim3(768), 512, 0, stream>>>(Xb, WqkvT, bqkv, (__hip_bfloat16*)QKVb, 8192, 3072, 1024);

  // --- fused attention (ctx overwrites Xb) ---
  attn_flash<<<dim3(8, 16, 16), 256, 0, stream>>>(QKVb, QKVb + 1024, QKVb + 2048, mask,
                                                  (__hip_bfloat16*)Xb, 3072);

  // --- self-output dense + residual -> bf16 pre-LN1 (d_out scratch), LN1 -> bf16 QKVb ---
  gemm_wo<<<dim3(512), 256, 0, stream>>>(Xb, WoT, bo, X, (__hip_bfloat16*)out, 8192, 1024, 1024);
  ln_attn<<<dim3(8192), 256, 0, stream>>>((const unsigned short*)out, g1, b1, (unsigned short*)QKVb);

  // --- intermediate dense + gelu ---
  gemm_wi<<<dim3(1024), 512, 0, stream>>>(QKVb, WiT, bi, (__hip_bfloat16*)I1, 8192, 4096, 1024);

  // --- output dense + bf16 residual -> bf16 pre-LN2 (Xb), LN2 -> f32 d_out ---
  gemm_wo2<<<dim3(512), 256, 0, stream>>>(I1, Wo2T, bo2, (const unsigned short*)QKVb,
                                          (__hip_bfloat16*)Xb, 8192, 1024, 4096);
  ln_ffn<<<dim3(8192), 256, 0, stream>>>((const unsigned short*)Xb, g2, b2, out);
}